// Round 1
// baseline (125.322 us; speedup 1.0000x reference)
//
#include <hip/hip_runtime.h>

namespace {
constexpr int BHW = 16384;   // 16*32*32 pixels
constexpr int L   = 8;       // latent dims
constexpr int K   = 512;     // codes per latent dim
constexpr int D   = 16;      // channel dim per latent
constexpr int HW  = 1024;    // 32*32
constexpr int CH  = 128;     // L*D
constexpr int TPB = 128;     // threads per block (2 waves)

__global__ __launch_bounds__(TPB) void soft_hard_encode(
    const float* __restrict__ z,      // [16,128,32,32]
    const float* __restrict__ codes,  // [8,512,16]
    float* __restrict__ out)          // soft[BHW*CH] | hard[BHW*CH] | idx[BHW*L] (as float)
{
    __shared__ float lds_c[K][D];   // 32 KB: codes for this block's l
    __shared__ float lds_w2[K];     // 2 KB: ||code||^2

    const int l = blockIdx.y;
    const int p = blockIdx.x * TPB + threadIdx.x;   // pixel index 0..16383

    // ---- stage codes[l] into LDS (vectorized, coalesced) ----
    {
        const float4* src = reinterpret_cast<const float4*>(codes + (size_t)l * K * D);
        float4* dst = reinterpret_cast<float4*>(&lds_c[0][0]);
        #pragma unroll
        for (int i = 0; i < (K * D / 4) / TPB; ++i)
            dst[threadIdx.x + i * TPB] = src[threadIdx.x + i * TPB];
    }
    __syncthreads();
    // ---- precompute ||c||^2 per code ----
    #pragma unroll
    for (int kk = 0; kk < K / TPB; ++kk) {
        const int k = threadIdx.x + kk * TPB;
        float w2 = 0.f;
        #pragma unroll
        for (int d = 0; d < D; ++d) w2 = fmaf(lds_c[k][d], lds_c[k][d], w2);
        lds_w2[k] = w2;
    }
    __syncthreads();

    // ---- load h (16 floats, stride HW over channels; coalesced across lanes) ----
    const int b  = p >> 10;          // pixel / 1024
    const int yx = p & (HW - 1);
    const float* zp = z + ((size_t)(b * CH + l * D)) * HW + yx;
    float h[D];
    #pragma unroll
    for (int d = 0; d < D; ++d) h[d] = zp[(size_t)d * HW];
    float h2 = 0.f;
    #pragma unroll
    for (int d = 0; d < D; ++d) h2 = fmaf(h[d], h[d], h2);

    // ---- online softmin over K codes ----
    float m = 1e30f;     // running min distance
    int   bestk = 0;
    float s = 0.f;       // sum of exp(m - dist)
    float acc[D];
    #pragma unroll
    for (int d = 0; d < D; ++d) acc[d] = 0.f;

    #pragma unroll 2
    for (int k = 0; k < K; ++k) {
        const float4* crow = reinterpret_cast<const float4*>(&lds_c[k][0]);
        float4 c0 = crow[0], c1 = crow[1], c2 = crow[2], c3 = crow[3];
        float c[D] = {c0.x, c0.y, c0.z, c0.w, c1.x, c1.y, c1.z, c1.w,
                      c2.x, c2.y, c2.z, c2.w, c3.x, c3.y, c3.z, c3.w};
        float cross = 0.f;
        #pragma unroll
        for (int d = 0; d < D; ++d) cross = fmaf(h[d], c[d], cross);
        // match reference formula: (h2 - 2*cross) + w2, clip, sqrt
        float d2 = (h2 - 2.f * cross) + lds_w2[k];
        d2 = fmaxf(d2, 1e-12f);
        float dist = sqrtf(d2);

        if (dist < m) {   // new running min: rescale existing sums (rare)
            float f = __expf(dist - m);     // first iter: exp(-1e30) = 0
            s = fmaf(s, f, 1.f);
            #pragma unroll
            for (int d = 0; d < D; ++d) acc[d] = fmaf(acc[d], f, c[d]);
            m = dist;
            bestk = k;
        } else {
            float w = __expf(m - dist);
            s += w;
            #pragma unroll
            for (int d = 0; d < D; ++d) acc[d] = fmaf(w, c[d], acc[d]);
        }
    }

    // ---- epilogue ----
    const float invs = 1.f / s;

    float* osoft = out + (size_t)p * CH + l * D;
    #pragma unroll
    for (int q = 0; q < 4; ++q) {
        float4 v;
        v.x = acc[q * 4 + 0] * invs;
        v.y = acc[q * 4 + 1] * invs;
        v.z = acc[q * 4 + 2] * invs;
        v.w = acc[q * 4 + 3] * invs;
        reinterpret_cast<float4*>(osoft)[q] = v;
    }

    const float4* bc = reinterpret_cast<const float4*>(&lds_c[bestk][0]);
    float* ohard = out + (size_t)BHW * CH + (size_t)p * CH + l * D;
    #pragma unroll
    for (int q = 0; q < 4; ++q)
        reinterpret_cast<float4*>(ohard)[q] = bc[q];

    out[(size_t)2 * BHW * CH + (size_t)p * L + l] = (float)bestk;
}
} // namespace

extern "C" void kernel_launch(void* const* d_in, const int* in_sizes, int n_in,
                              void* d_out, int out_size, void* d_ws, size_t ws_size,
                              hipStream_t stream) {
    const float* z     = (const float*)d_in[0];
    const float* codes = (const float*)d_in[1];
    float* out         = (float*)d_out;
    dim3 grid(BHW / TPB, L);
    soft_hard_encode<<<grid, TPB, 0, stream>>>(z, codes, out);
}

// Round 3
// 110.318 us; speedup vs baseline: 1.1360x; 1.1360x over previous
//
#include <hip/hip_runtime.h>

namespace {
constexpr int BHW = 16384;   // 16*32*32 pixels
constexpr int L   = 8;
constexpr int K   = 512;
constexpr int D   = 16;
constexpr int HW  = 1024;    // 32*32
constexpr int CH  = 128;     // L*D
constexpr int TPB = 256;     // 4 waves: waves 0-1 = K-half 0, waves 2-3 = K-half 1
constexpr int PPB = 128;     // pixels per block
constexpr int KHALF = K / 2;

// ---- tiny precompute: ||code||^2 for all 8*512 codes into workspace ----
// NOTE: sequential fmaf chain over d — must match the main-kernel association
// used in round 1 (argmin is sensitive to rounding order vs the np reference).
__global__ void compute_w2(const float* __restrict__ codes, float* __restrict__ w2) {
    int i = blockIdx.x * 256 + threadIdx.x;          // 0..4095
    const float* c = codes + (size_t)i * D;
    float s = 0.f;
    #pragma unroll
    for (int d = 0; d < D; ++d) s = fmaf(c[d], c[d], s);
    w2[i] = s;
}

__global__ __launch_bounds__(TPB, 4) void soft_hard_encode(
    const float* __restrict__ z,      // [16,128,32,32]
    const float* __restrict__ codes,  // [8,512,16]
    const float* __restrict__ w2g,    // [8,512]
    float* __restrict__ out)          // soft | hard | idx(float)
{
    __shared__ float part[PPB][19];   // half-1 partials: s, m, bestk, acc[16]

    const int tid  = threadIdx.x;
    const int lane = tid & 63;
    const int wv   = __builtin_amdgcn_readfirstlane(tid) >> 6;  // 0..3, uniform
    const int half = wv >> 1;        // uniform: which K-half
    const int pgrp = wv & 1;         // uniform: which pixel group
    const int l    = blockIdx.y;
    const int prow = pgrp * 64 + lane;               // 0..127 within block
    const int p    = blockIdx.x * PPB + prow;        // global pixel

    // ---- load h (coalesced across lanes; stride HW over channels) ----
    const int b  = p >> 10;
    const int yx = p & (HW - 1);
    const float* zp = z + ((size_t)(b * CH + l * D)) * HW + yx;
    float h[D];
    #pragma unroll
    for (int d = 0; d < D; ++d) h[d] = zp[(size_t)d * HW];
    float h2 = 0.f;
    #pragma unroll
    for (int d = 0; d < D; ++d) h2 = fmaf(h[d], h[d], h2);

    // ---- this wave's K range (wave-uniform -> scalar loads for codes) ----
    const int kbeg = half * KHALF;
    const float* __restrict__ crow = codes + ((size_t)l * K + kbeg) * D;
    const float* __restrict__ w2p  = w2g + l * K + kbeg;

    float m = 1e30f;
    int   bestk = 0;
    float s = 0.f;
    float acc[D];
    #pragma unroll
    for (int d = 0; d < D; ++d) acc[d] = 0.f;

    #pragma unroll 2
    for (int k = 0; k < KHALF; ++k) {
        float c[D];
        #pragma unroll
        for (int d = 0; d < D; ++d) c[d] = crow[k * D + d];   // uniform -> s_load
        const float w2k = w2p[k];                              // uniform -> s_load

        // ---- EXACT round-1 association: single sequential fmaf chain ----
        float cross = 0.f;
        #pragma unroll
        for (int d = 0; d < D; ++d) cross = fmaf(h[d], c[d], cross);
        float d2 = (h2 - 2.f * cross) + w2k;
        d2 = fmaxf(d2, 1e-12f);
        const float dist = sqrtf(d2);

        // branchless argmin (strict < keeps first occurrence)
        const bool lt = dist < m;
        m     = lt ? dist : m;
        bestk = lt ? k : bestk;

        // fixed-reference softmin weight (normalized by s at the end)
        const float w = __expf(-dist);
        s += w;
        #pragma unroll
        for (int d = 0; d < D; ++d) acc[d] = fmaf(w, c[d], acc[d]);
    }

    // ---- merge K-halves via LDS ----
    if (half == 1) {
        part[prow][0] = s;
        part[prow][1] = m;
        part[prow][2] = __int_as_float(bestk + KHALF);
        #pragma unroll
        for (int d = 0; d < D; ++d) part[prow][3 + d] = acc[d];
    }
    __syncthreads();
    if (half == 0) {
        const float s1 = part[prow][0];
        const float m1 = part[prow][1];
        const int   k1 = __float_as_int(part[prow][2]);
        s += s1;
        #pragma unroll
        for (int d = 0; d < D; ++d) acc[d] += part[prow][3 + d];
        if (m1 < m) { m = m1; bestk = k1; }   // tie -> lower half (first occurrence)

        const float invs = 1.f / s;
        float* osoft = out + (size_t)p * CH + l * D;
        #pragma unroll
        for (int q = 0; q < 4; ++q) {
            float4 v;
            v.x = acc[q * 4 + 0] * invs;
            v.y = acc[q * 4 + 1] * invs;
            v.z = acc[q * 4 + 2] * invs;
            v.w = acc[q * 4 + 3] * invs;
            reinterpret_cast<float4*>(osoft)[q] = v;
        }

        const float4* bc = reinterpret_cast<const float4*>(codes + ((size_t)l * K + bestk) * D);
        float* ohard = out + (size_t)BHW * CH + (size_t)p * CH + l * D;
        #pragma unroll
        for (int q = 0; q < 4; ++q)
            reinterpret_cast<float4*>(ohard)[q] = bc[q];

        out[(size_t)2 * BHW * CH + (size_t)p * L + l] = (float)bestk;
    }
}
} // namespace

extern "C" void kernel_launch(void* const* d_in, const int* in_sizes, int n_in,
                              void* d_out, int out_size, void* d_ws, size_t ws_size,
                              hipStream_t stream) {
    const float* z     = (const float*)d_in[0];
    const float* codes = (const float*)d_in[1];
    float* out         = (float*)d_out;
    float* w2          = (float*)d_ws;   // 8*512 floats = 16 KB

    compute_w2<<<dim3(L * K / 256), 256, 0, stream>>>(codes, w2);
    dim3 grid(BHW / PPB, L);
    soft_hard_encode<<<grid, TPB, 0, stream>>>(z, codes, w2, out);
}

// Round 4
// 98.188 us; speedup vs baseline: 1.2764x; 1.1235x over previous
//
#include <hip/hip_runtime.h>

namespace {
constexpr int BHW = 16384;   // 16*32*32 pixels
constexpr int L   = 8;
constexpr int K   = 512;
constexpr int D   = 16;
constexpr int HW  = 1024;    // 32*32
constexpr int CH  = 128;     // L*D
constexpr int TPB = 512;     // 8 waves = 2 pixel-groups x 4 K-quarters
constexpr int PPB = 128;     // pixels per block
constexpr int KQ  = K / 4;   // 128 codes per wave

// ---- tiny precompute: ||code||^2, sequential fmaf chain (rounding contract) ----
__global__ void compute_w2(const float* __restrict__ codes, float* __restrict__ w2) {
    int i = blockIdx.x * 256 + threadIdx.x;          // 0..4095
    const float* c = codes + (size_t)i * D;
    float s = 0.f;
    #pragma unroll
    for (int d = 0; d < D; ++d) s = fmaf(c[d], c[d], s);
    w2[i] = s;
}

__global__ __launch_bounds__(TPB, 8) void soft_hard_encode(
    const float* __restrict__ z,      // [16,128,32,32]
    const float* __restrict__ codes,  // [8,512,16]
    const float* __restrict__ w2g,    // [8,512]
    float* __restrict__ out)          // soft | hard | idx(float)
{
    __shared__ float part[3][PPB][19];   // quarters 1..3: s, m, bestk, acc[16]

    const int tid  = threadIdx.x;
    const int lane = tid & 63;
    const int wv   = __builtin_amdgcn_readfirstlane(tid) >> 6;  // 0..7, uniform
    const int q    = wv & 3;         // uniform: K-quarter
    const int pgrp = wv >> 2;        // uniform: pixel group
    const int l    = blockIdx.y;
    const int prow = pgrp * 64 + lane;               // 0..127 within block
    const int p    = blockIdx.x * PPB + prow;        // global pixel

    // ---- load h (coalesced across lanes; stride HW over channels) ----
    const int b  = p >> 10;
    const int yx = p & (HW - 1);
    const float* zp = z + ((size_t)(b * CH + l * D)) * HW + yx;
    float h[D];
    #pragma unroll
    for (int d = 0; d < D; ++d) h[d] = zp[(size_t)d * HW];
    float h2 = 0.f;
    #pragma unroll
    for (int d = 0; d < D; ++d) h2 = fmaf(h[d], h[d], h2);

    // ---- this wave's K range (wave-uniform -> scalar loads for codes) ----
    const int kbeg = q * KQ;
    const float* __restrict__ crow = codes + ((size_t)l * K + kbeg) * D;
    const float* __restrict__ w2p  = w2g + l * K + kbeg;

    float m = 1e30f;
    int   bestk = 0;
    float s = 0.f;
    float acc[D];
    #pragma unroll
    for (int d = 0; d < D; ++d) acc[d] = 0.f;

    #pragma unroll 2
    for (int k = 0; k < KQ; ++k) {
        float c[D];
        #pragma unroll
        for (int d = 0; d < D; ++d) c[d] = crow[k * D + d];   // uniform -> s_load
        const float w2k = w2p[k];                              // uniform -> s_load

        // ---- rounding contract: single sequential fmaf chain ----
        float cross = 0.f;
        #pragma unroll
        for (int d = 0; d < D; ++d) cross = fmaf(h[d], c[d], cross);
        float d2 = (h2 - 2.f * cross) + w2k;
        d2 = fmaxf(d2, 1e-12f);
        const float dist = sqrtf(d2);

        // branchless argmin (strict < keeps first occurrence)
        const bool lt = dist < m;
        m     = lt ? dist : m;
        bestk = lt ? k : bestk;

        // fixed-reference softmin weight (normalized by s at the end)
        const float w = __expf(-dist);
        s += w;
        #pragma unroll
        for (int d = 0; d < D; ++d) acc[d] = fmaf(w, c[d], acc[d]);
    }

    // ---- merge K-quarters via LDS (index order -> first-occurrence argmin) ----
    if (q != 0) {
        float* dst = &part[q - 1][prow][0];
        dst[0] = s;
        dst[1] = m;
        dst[2] = __int_as_float(bestk + kbeg);
        #pragma unroll
        for (int d = 0; d < D; ++d) dst[3 + d] = acc[d];
    }
    __syncthreads();
    if (q == 0) {
        #pragma unroll
        for (int j = 0; j < 3; ++j) {
            const float* src = &part[j][prow][0];
            s += src[0];
            const float mj = src[1];
            const int   kj = __float_as_int(src[2]);
            if (mj < m) { m = mj; bestk = kj; }   // tie -> lower quarter
            #pragma unroll
            for (int d = 0; d < D; ++d) acc[d] += src[3 + d];
        }

        const float invs = 1.f / s;
        float* osoft = out + (size_t)p * CH + l * D;
        #pragma unroll
        for (int qq = 0; qq < 4; ++qq) {
            float4 v;
            v.x = acc[qq * 4 + 0] * invs;
            v.y = acc[qq * 4 + 1] * invs;
            v.z = acc[qq * 4 + 2] * invs;
            v.w = acc[qq * 4 + 3] * invs;
            reinterpret_cast<float4*>(osoft)[qq] = v;
        }

        const float4* bc = reinterpret_cast<const float4*>(codes + ((size_t)l * K + bestk) * D);
        float* ohard = out + (size_t)BHW * CH + (size_t)p * CH + l * D;
        #pragma unroll
        for (int qq = 0; qq < 4; ++qq)
            reinterpret_cast<float4*>(ohard)[qq] = bc[qq];

        out[(size_t)2 * BHW * CH + (size_t)p * L + l] = (float)bestk;
    }
}
} // namespace

extern "C" void kernel_launch(void* const* d_in, const int* in_sizes, int n_in,
                              void* d_out, int out_size, void* d_ws, size_t ws_size,
                              hipStream_t stream) {
    const float* z     = (const float*)d_in[0];
    const float* codes = (const float*)d_in[1];
    float* out         = (float*)d_out;
    float* w2          = (float*)d_ws;   // 8*512 floats = 16 KB

    compute_w2<<<dim3(L * K / 256), 256, 0, stream>>>(codes, w2);
    dim3 grid(BHW / PPB, L);
    soft_hard_encode<<<grid, TPB, 0, stream>>>(z, codes, w2, out);
}

// Round 5
// 95.501 us; speedup vs baseline: 1.3123x; 1.0281x over previous
//
#include <hip/hip_runtime.h>

typedef float v2f __attribute__((ext_vector_type(2)));

namespace {
constexpr int BHW = 16384;   // 16*32*32 pixels
constexpr int L   = 8;
constexpr int K   = 512;
constexpr int D   = 16;
constexpr int HW  = 1024;    // 32*32
constexpr int CH  = 128;     // L*D
constexpr int TPB = 512;     // 8 waves = 2 pixel-groups x 4 K-quarters
constexpr int PPB = 128;     // pixels per block
constexpr int KQ  = K / 4;   // 128 codes per wave
constexpr int KP  = KQ / 2;  // 64 code-pairs per wave

// ws layout (packed path): [0, L*K*D) floats = codesP interleaved pairs,
//                          [L*K*D, L*K*D + L*K) floats = w2P pairs
constexpr size_t WS_CODESP = (size_t)L * K * D;          // 65536 floats
constexpr size_t WS_NEED   = (WS_CODESP + (size_t)L * K) * sizeof(float); // 272 KB

// ---- repack codes into pair-interleaved layout + ||c||^2 (sequential fmaf chain) ----
__global__ void repack(const float* __restrict__ codes,
                       float* __restrict__ codesP, float* __restrict__ w2P) {
    int i = blockIdx.x * 256 + threadIdx.x;          // 0..4095 over (l,k)
    int l = i >> 9, k = i & (K - 1);
    const float* c = codes + (size_t)i * D;
    float s = 0.f;
    #pragma unroll
    for (int d = 0; d < D; ++d) s = fmaf(c[d], c[d], s);
    int i2 = k >> 1, j = k & 1;
    float* dst = codesP + ((size_t)(l * (K / 2) + i2)) * (2 * D) + j;
    #pragma unroll
    for (int d = 0; d < D; ++d) dst[2 * d] = c[d];
    w2P[(l * (K / 2) + i2) * 2 + j] = s;
}

// ---- packed main kernel: 2 codes per iteration via v_pk_* f32 ----
__global__ __launch_bounds__(TPB, 4) void soft_hard_encode_pk(
    const float* __restrict__ z,
    const float* __restrict__ codes,    // original layout (hard-symbol fetch)
    const float* __restrict__ codesP,   // pair-interleaved
    const float* __restrict__ w2P,      // pair-interleaved ||c||^2
    float* __restrict__ out)
{
    __shared__ float part[3][PPB][19];

    const int tid  = threadIdx.x;
    const int lane = tid & 63;
    const int wv   = __builtin_amdgcn_readfirstlane(tid) >> 6;  // 0..7 uniform
    const int q    = wv & 3;
    const int pgrp = wv >> 2;
    const int l    = blockIdx.y;
    const int prow = pgrp * 64 + lane;
    const int p    = blockIdx.x * PPB + prow;

    const int b  = p >> 10;
    const int yx = p & (HW - 1);
    const float* zp = z + ((size_t)(b * CH + l * D)) * HW + yx;
    float h[D];
    #pragma unroll
    for (int d = 0; d < D; ++d) h[d] = zp[(size_t)d * HW];
    float h2 = 0.f;
    #pragma unroll
    for (int d = 0; d < D; ++d) h2 = fmaf(h[d], h[d], h2);

    v2f hp[D], accp[D];
    #pragma unroll
    for (int d = 0; d < D; ++d) { hp[d] = (v2f){h[d], h[d]}; accp[d] = (v2f){0.f, 0.f}; }
    const v2f h2p = (v2f){h2, h2};

    // wave-uniform pair range
    const int kbeg = q * KQ;
    const float* __restrict__ crowP = codesP + ((size_t)(l * (K / 2) + q * KP)) * (2 * D);
    const v2f*   __restrict__ w2pP  = reinterpret_cast<const v2f*>(w2P + (size_t)(l * (K / 2) + q * KP) * 2);

    float m = 1e30f;
    int   bestk = 0;
    v2f   sp = (v2f){0.f, 0.f};

    #pragma unroll 1
    for (int kp = 0; kp < KP; ++kp) {
        const v2f* cp = reinterpret_cast<const v2f*>(crowP + (size_t)kp * (2 * D));
        v2f c[D];
        #pragma unroll
        for (int d = 0; d < D; ++d) c[d] = cp[d];          // contiguous dwordx4 loads
        const v2f w2k = w2pP[kp];

        // rounding contract: each half is the exact sequential fmaf chain of R4
        v2f cross = (v2f){0.f, 0.f};
        #pragma unroll
        for (int d = 0; d < D; ++d)
            cross = __builtin_elementwise_fma(hp[d], c[d], cross);
        v2f d2 = (h2p - 2.f * cross) + w2k;                // same source form as R4
        d2 = __builtin_elementwise_max(d2, (v2f){1e-12f, 1e-12f});
        const float dist0 = sqrtf(d2.x);
        const float dist1 = sqrtf(d2.y);

        // sequential strict-< argmin (first occurrence preserved)
        const bool lt0 = dist0 < m;
        m     = lt0 ? dist0 : m;
        bestk = lt0 ? 2 * kp : bestk;
        const bool lt1 = dist1 < m;
        m     = lt1 ? dist1 : m;
        bestk = lt1 ? 2 * kp + 1 : bestk;

        const v2f w = (v2f){__expf(-dist0), __expf(-dist1)};
        sp += w;
        #pragma unroll
        for (int d = 0; d < D; ++d)
            accp[d] = __builtin_elementwise_fma(w, c[d], accp[d]);   // even/odd accs
    }

    float s = sp.x + sp.y;
    float acc[D];
    #pragma unroll
    for (int d = 0; d < D; ++d) acc[d] = accp[d].x + accp[d].y;
    bestk += kbeg;

    if (q != 0) {
        float* dst = &part[q - 1][prow][0];
        dst[0] = s;
        dst[1] = m;
        dst[2] = __int_as_float(bestk);
        #pragma unroll
        for (int d = 0; d < D; ++d) dst[3 + d] = acc[d];
    }
    __syncthreads();
    if (q == 0) {
        #pragma unroll
        for (int j = 0; j < 3; ++j) {
            const float* src = &part[j][prow][0];
            s += src[0];
            const float mj = src[1];
            const int   kj = __float_as_int(src[2]);
            if (mj < m) { m = mj; bestk = kj; }
            #pragma unroll
            for (int d = 0; d < D; ++d) acc[d] += src[3 + d];
        }

        const float invs = 1.f / s;
        float* osoft = out + (size_t)p * CH + l * D;
        #pragma unroll
        for (int qq = 0; qq < 4; ++qq) {
            float4 v;
            v.x = acc[qq * 4 + 0] * invs;
            v.y = acc[qq * 4 + 1] * invs;
            v.z = acc[qq * 4 + 2] * invs;
            v.w = acc[qq * 4 + 3] * invs;
            reinterpret_cast<float4*>(osoft)[qq] = v;
        }

        const float4* bc = reinterpret_cast<const float4*>(codes + ((size_t)l * K + bestk) * D);
        float* ohard = out + (size_t)BHW * CH + (size_t)p * CH + l * D;
        #pragma unroll
        for (int qq = 0; qq < 4; ++qq)
            reinterpret_cast<float4*>(ohard)[qq] = bc[qq];

        out[(size_t)2 * BHW * CH + (size_t)p * L + l] = (float)bestk;
    }
}

// ================= fallback (R4 scalar path, needs only 16 KB ws) =================
__global__ void compute_w2(const float* __restrict__ codes, float* __restrict__ w2) {
    int i = blockIdx.x * 256 + threadIdx.x;
    const float* c = codes + (size_t)i * D;
    float s = 0.f;
    #pragma unroll
    for (int d = 0; d < D; ++d) s = fmaf(c[d], c[d], s);
    w2[i] = s;
}

__global__ __launch_bounds__(TPB, 8) void soft_hard_encode(
    const float* __restrict__ z, const float* __restrict__ codes,
    const float* __restrict__ w2g, float* __restrict__ out)
{
    __shared__ float part[3][PPB][19];
    const int tid  = threadIdx.x;
    const int lane = tid & 63;
    const int wv   = __builtin_amdgcn_readfirstlane(tid) >> 6;
    const int q    = wv & 3;
    const int pgrp = wv >> 2;
    const int l    = blockIdx.y;
    const int prow = pgrp * 64 + lane;
    const int p    = blockIdx.x * PPB + prow;

    const int b  = p >> 10;
    const int yx = p & (HW - 1);
    const float* zp = z + ((size_t)(b * CH + l * D)) * HW + yx;
    float h[D];
    #pragma unroll
    for (int d = 0; d < D; ++d) h[d] = zp[(size_t)d * HW];
    float h2 = 0.f;
    #pragma unroll
    for (int d = 0; d < D; ++d) h2 = fmaf(h[d], h[d], h2);

    const int kbeg = q * KQ;
    const float* __restrict__ crow = codes + ((size_t)l * K + kbeg) * D;
    const float* __restrict__ w2p  = w2g + l * K + kbeg;

    float m = 1e30f; int bestk = 0; float s = 0.f;
    float acc[D];
    #pragma unroll
    for (int d = 0; d < D; ++d) acc[d] = 0.f;

    #pragma unroll 2
    for (int k = 0; k < KQ; ++k) {
        float c[D];
        #pragma unroll
        for (int d = 0; d < D; ++d) c[d] = crow[k * D + d];
        const float w2k = w2p[k];
        float cross = 0.f;
        #pragma unroll
        for (int d = 0; d < D; ++d) cross = fmaf(h[d], c[d], cross);
        float d2 = (h2 - 2.f * cross) + w2k;
        d2 = fmaxf(d2, 1e-12f);
        const float dist = sqrtf(d2);
        const bool lt = dist < m;
        m = lt ? dist : m; bestk = lt ? k : bestk;
        const float w = __expf(-dist);
        s += w;
        #pragma unroll
        for (int d = 0; d < D; ++d) acc[d] = fmaf(w, c[d], acc[d]);
    }

    if (q != 0) {
        float* dst = &part[q - 1][prow][0];
        dst[0] = s; dst[1] = m; dst[2] = __int_as_float(bestk + kbeg);
        #pragma unroll
        for (int d = 0; d < D; ++d) dst[3 + d] = acc[d];
    }
    __syncthreads();
    if (q == 0) {
        #pragma unroll
        for (int j = 0; j < 3; ++j) {
            const float* src = &part[j][prow][0];
            s += src[0];
            const float mj = src[1];
            const int kj = __float_as_int(src[2]);
            if (mj < m) { m = mj; bestk = kj; }
            #pragma unroll
            for (int d = 0; d < D; ++d) acc[d] += src[3 + d];
        }
        const float invs = 1.f / s;
        float* osoft = out + (size_t)p * CH + l * D;
        #pragma unroll
        for (int qq = 0; qq < 4; ++qq) {
            float4 v;
            v.x = acc[qq*4+0]*invs; v.y = acc[qq*4+1]*invs;
            v.z = acc[qq*4+2]*invs; v.w = acc[qq*4+3]*invs;
            reinterpret_cast<float4*>(osoft)[qq] = v;
        }
        const float4* bc = reinterpret_cast<const float4*>(codes + ((size_t)l * K + bestk) * D);
        float* ohard = out + (size_t)BHW * CH + (size_t)p * CH + l * D;
        #pragma unroll
        for (int qq = 0; qq < 4; ++qq)
            reinterpret_cast<float4*>(ohard)[qq] = bc[qq];
        out[(size_t)2 * BHW * CH + (size_t)p * L + l] = (float)bestk;
    }
}
} // namespace

extern "C" void kernel_launch(void* const* d_in, const int* in_sizes, int n_in,
                              void* d_out, int out_size, void* d_ws, size_t ws_size,
                              hipStream_t stream) {
    const float* z     = (const float*)d_in[0];
    const float* codes = (const float*)d_in[1];
    float* out         = (float*)d_out;
    dim3 grid(BHW / PPB, L);

    if (ws_size >= WS_NEED) {
        float* codesP = (float*)d_ws;
        float* w2P    = codesP + WS_CODESP;
        repack<<<dim3(L * K / 256), 256, 0, stream>>>(codes, codesP, w2P);
        soft_hard_encode_pk<<<grid, TPB, 0, stream>>>(z, codes, codesP, w2P, out);
    } else {
        float* w2 = (float*)d_ws;   // 16 KB
        compute_w2<<<dim3(L * K / 256), 256, 0, stream>>>(codes, w2);
        soft_hard_encode<<<grid, TPB, 0, stream>>>(z, codes, w2, out);
    }
}

// Round 6
// 88.465 us; speedup vs baseline: 1.4166x; 1.0795x over previous
//
#include <hip/hip_runtime.h>

namespace {
constexpr int BHW = 16384;   // 16*32*32 pixels
constexpr int L   = 8;
constexpr int K   = 512;
constexpr int D   = 16;
constexpr int HW  = 1024;    // 32*32
constexpr int CH  = 128;     // L*D
constexpr int TPB = 512;     // 8 waves = 2 pixel-groups x 4 K-quarters
constexpr int PPB = 128;     // pixels per block
constexpr int KQ  = K / 4;   // 128 codes per wave

// ---- tiny precompute: ||code||^2, sequential fmaf chain (rounding contract) ----
__global__ void compute_w2(const float* __restrict__ codes, float* __restrict__ w2) {
    int i = blockIdx.x * 256 + threadIdx.x;          // 0..4095
    const float* c = codes + (size_t)i * D;
    float s = 0.f;
    #pragma unroll
    for (int d = 0; d < D; ++d) s = fmaf(c[d], c[d], s);
    w2[i] = s;
}

__global__ __launch_bounds__(TPB, 8) void soft_hard_encode(
    const float* __restrict__ z,      // [16,128,32,32]
    const float* __restrict__ codes,  // [8,512,16]
    const float* __restrict__ w2g,    // [8,512]
    float* __restrict__ out)          // soft | hard | idx(float)
{
    __shared__ float part[3][PPB][21];   // quarters 1..3: s, m2, m2b, ka, kb, acc[16]

    const int tid  = threadIdx.x;
    const int lane = tid & 63;
    const int wv   = __builtin_amdgcn_readfirstlane(tid) >> 6;  // 0..7, uniform
    const int q    = wv & 3;         // uniform: K-quarter
    const int pgrp = wv >> 2;        // uniform: pixel group
    const int l    = blockIdx.y;
    const int prow = pgrp * 64 + lane;               // 0..127 within block
    const int p    = blockIdx.x * PPB + prow;        // global pixel

    // ---- load h (coalesced across lanes; stride HW over channels) ----
    const int b  = p >> 10;
    const int yx = p & (HW - 1);
    const float* zp = z + ((size_t)(b * CH + l * D)) * HW + yx;
    float h[D];
    #pragma unroll
    for (int d = 0; d < D; ++d) h[d] = zp[(size_t)d * HW];
    float h2 = 0.f;
    #pragma unroll
    for (int d = 0; d < D; ++d) h2 = fmaf(h[d], h[d], h2);

    // ---- this wave's K range (wave-uniform -> scalar loads for codes) ----
    const int kbeg = q * KQ;
    const float* __restrict__ crow = codes + ((size_t)l * K + kbeg) * D;
    const float* __restrict__ w2p  = w2g + l * K + kbeg;

    // min / second-min of CLAMPED d2, with first-occurrence indices
    float m2 = 1e30f, m2b = 1e30f;
    int   ka = 0,     kb = 0;
    float s = 0.f;
    float acc[D];
    #pragma unroll
    for (int d = 0; d < D; ++d) acc[d] = 0.f;

    #pragma unroll 2
    for (int k = 0; k < KQ; ++k) {
        float c[D];
        #pragma unroll
        for (int d = 0; d < D; ++d) c[d] = crow[k * D + d];   // uniform -> s_load
        const float w2k = w2p[k];                              // uniform -> s_load

        // ---- rounding contract: single sequential fmaf chain (UNCHANGED) ----
        float cross = 0.f;
        #pragma unroll
        for (int d = 0; d < D; ++d) cross = fmaf(h[d], c[d], cross);
        float d2 = (h2 - 2.f * cross) + w2k;
        d2 = fmaxf(d2, 1e-12f);

        // ---- exact (min, min2) tracking on d2 (monotone under sqrt) ----
        const bool lt  = d2 < m2;
        const bool lt2 = d2 < m2b;
        m2b = lt2 ? d2 : m2b;  kb = lt2 ? k  : kb;
        m2b = lt  ? m2 : m2b;  kb = lt  ? ka : kb;   // old best demotes to 2nd
        m2  = lt  ? d2 : m2;   ka = lt  ? k  : ka;

        // ---- soft path: fast sqrt + exp2 (loose tolerance) ----
        const float dist = __builtin_amdgcn_sqrtf(d2);
        const float w = __builtin_amdgcn_exp2f(dist * -1.44269504088896340736f);
        s += w;
        #pragma unroll
        for (int d = 0; d < D; ++d) acc[d] = fmaf(w, c[d], acc[d]);
    }

    // ---- merge K-quarters via LDS (increasing-quarter order -> index order) ----
    if (q != 0) {
        float* dst = &part[q - 1][prow][0];
        dst[0] = s;
        dst[1] = m2;
        dst[2] = m2b;
        dst[3] = __int_as_float(ka + kbeg);
        dst[4] = __int_as_float(kb + kbeg);
        #pragma unroll
        for (int d = 0; d < D; ++d) dst[5 + d] = acc[d];
    }
    __syncthreads();
    if (q == 0) {
        #pragma unroll
        for (int j = 0; j < 3; ++j) {
            const float* src = &part[j][prow][0];
            s += src[0];
            const float v1 = src[1], v2 = src[2];
            const int   i1 = __float_as_int(src[3]);
            const int   i2 = __float_as_int(src[4]);
            // merge (v1,i1) then (v2,i2); incoming indices all exceed current
            {
                const bool lt = v1 < m2, lt2 = v1 < m2b;
                m2b = lt2 ? v1 : m2b;  kb = lt2 ? i1 : kb;
                m2b = lt  ? m2 : m2b;  kb = lt  ? ka : kb;
                m2  = lt  ? v1 : m2;   ka = lt  ? i1 : ka;
            }
            {
                const bool lt = v2 < m2, lt2 = v2 < m2b;
                m2b = lt2 ? v2 : m2b;  kb = lt2 ? i2 : kb;
                m2b = lt  ? m2 : m2b;  kb = lt  ? ka : kb;
                m2  = lt  ? v2 : m2;   ka = lt  ? i2 : ka;
            }
            #pragma unroll
            for (int d = 0; d < D; ++d) acc[d] += src[5 + d];
        }

        // ---- exact np tie semantics: two precise sqrts per row ----
        const float dmin = sqrtf(m2);
        const float d2nd = sqrtf(m2b);
        int bestk = (dmin == d2nd) ? min(ka, kb) : ka;

        const float invs = 1.f / s;
        float* osoft = out + (size_t)p * CH + l * D;
        #pragma unroll
        for (int qq = 0; qq < 4; ++qq) {
            float4 v;
            v.x = acc[qq * 4 + 0] * invs;
            v.y = acc[qq * 4 + 1] * invs;
            v.z = acc[qq * 4 + 2] * invs;
            v.w = acc[qq * 4 + 3] * invs;
            reinterpret_cast<float4*>(osoft)[qq] = v;
        }

        const float4* bc = reinterpret_cast<const float4*>(codes + ((size_t)l * K + bestk) * D);
        float* ohard = out + (size_t)BHW * CH + (size_t)p * CH + l * D;
        #pragma unroll
        for (int qq = 0; qq < 4; ++qq)
            reinterpret_cast<float4*>(ohard)[qq] = bc[qq];

        out[(size_t)2 * BHW * CH + (size_t)p * L + l] = (float)bestk;
    }
}
} // namespace

extern "C" void kernel_launch(void* const* d_in, const int* in_sizes, int n_in,
                              void* d_out, int out_size, void* d_ws, size_t ws_size,
                              hipStream_t stream) {
    const float* z     = (const float*)d_in[0];
    const float* codes = (const float*)d_in[1];
    float* out         = (float*)d_out;
    float* w2          = (float*)d_ws;   // 8*512 floats = 16 KB

    compute_w2<<<dim3(L * K / 256), 256, 0, stream>>>(codes, w2);
    dim3 grid(BHW / PPB, L);
    soft_hard_encode<<<grid, TPB, 0, stream>>>(z, codes, w2, out);
}

// Round 7
// 88.262 us; speedup vs baseline: 1.4199x; 1.0023x over previous
//
#include <hip/hip_runtime.h>

typedef float v2f __attribute__((ext_vector_type(2)));

namespace {
constexpr int BHW = 16384;   // 16*32*32 pixels
constexpr int L   = 8;
constexpr int K   = 512;
constexpr int D   = 16;
constexpr int HW  = 1024;    // 32*32
constexpr int CH  = 128;     // L*D
constexpr int TPB = 512;     // 8 waves = 2 pixel-groups x 4 K-quarters
constexpr int PPB = 128;     // pixels per block
constexpr int KQ  = K / 4;   // 128 codes per wave

// ---- tiny precompute: ||code||^2, sequential fmaf chain (rounding contract) ----
__global__ void compute_w2(const float* __restrict__ codes, float* __restrict__ w2) {
    int i = blockIdx.x * 256 + threadIdx.x;          // 0..4095
    const float* c = codes + (size_t)i * D;
    float s = 0.f;
    #pragma unroll
    for (int d = 0; d < D; ++d) s = fmaf(c[d], c[d], s);
    w2[i] = s;
}

__global__ __launch_bounds__(TPB, 8) void soft_hard_encode(
    const float* __restrict__ z,      // [16,128,32,32]
    const float* __restrict__ codes,  // [8,512,16]
    const float* __restrict__ w2g,    // [8,512]
    float* __restrict__ out)          // soft | hard | idx(float)
{
    __shared__ float part[3][PPB][21];   // quarters 1..3: s, m2, m2b, ka, kb, acc[16]

    const int tid  = threadIdx.x;
    const int lane = tid & 63;
    const int wv   = __builtin_amdgcn_readfirstlane(tid) >> 6;  // 0..7, uniform
    const int q    = wv & 3;         // uniform: K-quarter
    const int pgrp = wv >> 2;        // uniform: pixel group
    const int l    = blockIdx.y;
    const int prow = pgrp * 64 + lane;               // 0..127 within block
    const int p    = blockIdx.x * PPB + prow;        // global pixel

    // ---- load h (coalesced across lanes; stride HW over channels) ----
    const int b  = p >> 10;
    const int yx = p & (HW - 1);
    const float* zp = z + ((size_t)(b * CH + l * D)) * HW + yx;
    float h[D];
    #pragma unroll
    for (int d = 0; d < D; ++d) h[d] = zp[(size_t)d * HW];
    float h2 = 0.f;
    #pragma unroll
    for (int d = 0; d < D; ++d) h2 = fmaf(h[d], h[d], h2);

    // ---- this wave's K range (wave-uniform -> scalar loads for codes) ----
    const int kbeg = q * KQ;
    const float* __restrict__ crow = codes + ((size_t)l * K + kbeg) * D;
    const float* __restrict__ w2p  = w2g + l * K + kbeg;

    // min / second-min of CLAMPED d2, with first-occurrence indices
    float m2 = 1e30f, m2b = 1e30f;
    int   ka = 0,     kb = 0;
    float s = 0.f;
    v2f accp[D / 2];                 // packed even/odd accumulator (bit-exact vs scalar)
    #pragma unroll
    for (int i = 0; i < D / 2; ++i) accp[i] = (v2f){0.f, 0.f};

    #pragma unroll 4
    for (int k = 0; k < KQ; ++k) {
        float c[D];
        #pragma unroll
        for (int d = 0; d < D; ++d) c[d] = crow[k * D + d];   // uniform -> s_load
        const float w2k = w2p[k];                              // uniform -> s_load

        // ---- rounding contract: single sequential fmaf chain (UNCHANGED) ----
        float cross = 0.f;
        #pragma unroll
        for (int d = 0; d < D; ++d) cross = fmaf(h[d], c[d], cross);
        float d2 = (h2 - 2.f * cross) + w2k;
        d2 = fmaxf(d2, 1e-12f);

        // ---- exact (min, min2) tracking on d2 (monotone under sqrt) ----
        const bool lt  = d2 < m2;
        const bool lt2 = d2 < m2b;
        m2b = lt2 ? d2 : m2b;  kb = lt2 ? k  : kb;
        m2b = lt  ? m2 : m2b;  kb = lt  ? ka : kb;   // old best demotes to 2nd
        m2  = lt  ? d2 : m2;   ka = lt  ? k  : ka;

        // ---- soft path: fast sqrt + exp2 (loose tolerance) ----
        const float dist = __builtin_amdgcn_sqrtf(d2);
        const float w = __builtin_amdgcn_exp2f(dist * -1.44269504088896340736f);
        s += w;
        // packed accumulate: accp[i].x == old acc[2i], accp[i].y == old acc[2i+1]
        const v2f wp = (v2f){w, w};
        #pragma unroll
        for (int i = 0; i < D / 2; ++i) {
            const v2f cp = (v2f){c[2 * i], c[2 * i + 1]};
            accp[i] = __builtin_elementwise_fma(wp, cp, accp[i]);
        }
    }

    float acc[D];
    #pragma unroll
    for (int i = 0; i < D / 2; ++i) { acc[2 * i] = accp[i].x; acc[2 * i + 1] = accp[i].y; }

    // ---- merge K-quarters via LDS (increasing-quarter order -> index order) ----
    if (q != 0) {
        float* dst = &part[q - 1][prow][0];
        dst[0] = s;
        dst[1] = m2;
        dst[2] = m2b;
        dst[3] = __int_as_float(ka + kbeg);
        dst[4] = __int_as_float(kb + kbeg);
        #pragma unroll
        for (int d = 0; d < D; ++d) dst[5 + d] = acc[d];
    }
    __syncthreads();
    if (q == 0) {
        #pragma unroll
        for (int j = 0; j < 3; ++j) {
            const float* src = &part[j][prow][0];
            s += src[0];
            const float v1 = src[1], v2 = src[2];
            const int   i1 = __float_as_int(src[3]);
            const int   i2 = __float_as_int(src[4]);
            {
                const bool lt = v1 < m2, lt2 = v1 < m2b;
                m2b = lt2 ? v1 : m2b;  kb = lt2 ? i1 : kb;
                m2b = lt  ? m2 : m2b;  kb = lt  ? ka : kb;
                m2  = lt  ? v1 : m2;   ka = lt  ? i1 : ka;
            }
            {
                const bool lt = v2 < m2, lt2 = v2 < m2b;
                m2b = lt2 ? v2 : m2b;  kb = lt2 ? i2 : kb;
                m2b = lt  ? m2 : m2b;  kb = lt  ? ka : kb;
                m2  = lt  ? v2 : m2;   ka = lt  ? i2 : ka;
            }
            #pragma unroll
            for (int d = 0; d < D; ++d) acc[d] += src[5 + d];
        }

        // ---- exact np tie semantics: two precise sqrts per row ----
        const float dmin = sqrtf(m2);
        const float d2nd = sqrtf(m2b);
        int bestk = (dmin == d2nd) ? min(ka, kb) : ka;

        const float invs = 1.f / s;
        float* osoft = out + (size_t)p * CH + l * D;
        #pragma unroll
        for (int qq = 0; qq < 4; ++qq) {
            float4 v;
            v.x = acc[qq * 4 + 0] * invs;
            v.y = acc[qq * 4 + 1] * invs;
            v.z = acc[qq * 4 + 2] * invs;
            v.w = acc[qq * 4 + 3] * invs;
            reinterpret_cast<float4*>(osoft)[qq] = v;
        }

        const float4* bc = reinterpret_cast<const float4*>(codes + ((size_t)l * K + bestk) * D);
        float* ohard = out + (size_t)BHW * CH + (size_t)p * CH + l * D;
        #pragma unroll
        for (int qq = 0; qq < 4; ++qq)
            reinterpret_cast<float4*>(ohard)[qq] = bc[qq];

        out[(size_t)2 * BHW * CH + (size_t)p * L + l] = (float)bestk;
    }
}
} // namespace

extern "C" void kernel_launch(void* const* d_in, const int* in_sizes, int n_in,
                              void* d_out, int out_size, void* d_ws, size_t ws_size,
                              hipStream_t stream) {
    const float* z     = (const float*)d_in[0];
    const float* codes = (const float*)d_in[1];
    float* out         = (float*)d_out;
    float* w2          = (float*)d_ws;   // 8*512 floats = 16 KB

    compute_w2<<<dim3(L * K / 256), 256, 0, stream>>>(codes, w2);
    dim3 grid(BHW / PPB, L);
    soft_hard_encode<<<grid, TPB, 0, stream>>>(z, codes, w2, out);
}

// Round 8
// 85.282 us; speedup vs baseline: 1.4695x; 1.0349x over previous
//
#include <hip/hip_runtime.h>

namespace {
constexpr int BHW = 16384;   // 16*32*32 pixels
constexpr int L   = 8;
constexpr int K   = 512;
constexpr int D   = 16;
constexpr int HW  = 1024;    // 32*32
constexpr int CH  = 128;     // L*D
constexpr int TPB = 512;     // 8 waves = 2 pixel-groups x 4 K-quarters
constexpr int PPB = 128;     // pixels per block
constexpr int KQ  = K / 4;   // 128 codes per wave

// ---- tiny precompute: ||code||^2, sequential fmaf chain (rounding contract) ----
__global__ void compute_w2(const float* __restrict__ codes, float* __restrict__ w2) {
    int i = blockIdx.x * 256 + threadIdx.x;          // 0..4095
    const float* c = codes + (size_t)i * D;
    float s = 0.f;
    #pragma unroll
    for (int d = 0; d < D; ++d) s = fmaf(c[d], c[d], s);
    w2[i] = s;
}

__global__ __launch_bounds__(TPB, 4) void soft_hard_encode(
    const float* __restrict__ z,      // [16,128,32,32]
    const float* __restrict__ codes,  // [8,512,16]
    const float* __restrict__ w2g,    // [8,512]
    float* __restrict__ out)          // soft | hard | idx(float)
{
    __shared__ float part[3][PPB][20];   // quarters 1..3: s, m2, m2b, ka, acc[16]

    const int tid  = threadIdx.x;
    const int lane = tid & 63;
    const int wv   = __builtin_amdgcn_readfirstlane(tid) >> 6;  // 0..7, uniform
    const int q    = wv & 3;         // uniform: K-quarter
    const int pgrp = wv >> 2;        // uniform: pixel group
    const int l    = blockIdx.y;
    const int prow = pgrp * 64 + lane;               // 0..127 within block
    const int p    = blockIdx.x * PPB + prow;        // global pixel

    // ---- load h (coalesced across lanes; stride HW over channels) ----
    const int b  = p >> 10;
    const int yx = p & (HW - 1);
    const float* zp = z + ((size_t)(b * CH + l * D)) * HW + yx;
    float h[D];
    #pragma unroll
    for (int d = 0; d < D; ++d) h[d] = zp[(size_t)d * HW];
    float h2 = 0.f;
    #pragma unroll
    for (int d = 0; d < D; ++d) h2 = fmaf(h[d], h[d], h2);

    // ---- this wave's K range (wave-uniform -> scalar loads for codes) ----
    const int kbeg = q * KQ;
    const float* __restrict__ crow = codes + ((size_t)l * K + kbeg) * D;
    const float* __restrict__ w2p  = w2g + l * K + kbeg;

    // min (with first-occurrence index) and second-min VALUE of clamped d2
    float m2 = 1e30f, m2b = 1e30f;
    int   ka = 0;
    float s = 0.f;
    float acc[D];
    #pragma unroll
    for (int d = 0; d < D; ++d) acc[d] = 0.f;

    #pragma unroll 4
    for (int k = 0; k < KQ; ++k) {
        float c[D];
        #pragma unroll
        for (int d = 0; d < D; ++d) c[d] = crow[k * D + d];   // uniform -> s_load
        const float w2k = w2p[k];                              // uniform -> s_load

        // ---- rounding contract: single sequential fmaf chain (UNCHANGED) ----
        float cross = 0.f;
        #pragma unroll
        for (int d = 0; d < D; ++d) cross = fmaf(h[d], c[d], cross);
        float d2 = (h2 - 2.f * cross) + w2k;
        d2 = fmaxf(d2, 1e-12f);

        // ---- lean exact min tracking on d2 ----
        const float t = fmaxf(d2, m2);     // old m2
        m2b = fminf(m2b, t);               // second-min value (no index)
        const bool lt = d2 < m2;
        m2 = lt ? d2 : m2;
        ka = lt ? k  : ka;

        // ---- soft path: fast sqrt + exp2 (loose tolerance) ----
        const float dist = __builtin_amdgcn_sqrtf(d2);
        const float w = __builtin_amdgcn_exp2f(dist * -1.44269504088896340736f);
        s += w;
        #pragma unroll
        for (int d = 0; d < D; ++d) acc[d] = fmaf(w, c[d], acc[d]);
    }

    // ---- merge K-quarters via LDS (increasing-quarter order -> index order) ----
    if (q != 0) {
        float* dst = &part[q - 1][prow][0];
        dst[0] = s;
        dst[1] = m2;
        dst[2] = m2b;
        dst[3] = __int_as_float(ka + kbeg);
        #pragma unroll
        for (int d = 0; d < D; ++d) dst[4 + d] = acc[d];
    }
    __syncthreads();
    if (q == 0) {
        #pragma unroll
        for (int j = 0; j < 3; ++j) {
            const float* src = &part[j][prow][0];
            s += src[0];
            const float mj  = src[1];
            const float mbj = src[2];
            const int   kj  = __float_as_int(src[3]);
            // global 2nd-min = min( max(minA,minB), min(min2A,min2B) )
            m2b = fminf(fminf(m2b, mbj), fmaxf(m2, mj));
            const bool lt = mj < m2;     // strict: tie keeps lower-quarter index
            m2 = lt ? mj : m2;
            ka = lt ? kj : ka;
            #pragma unroll
            for (int d = 0; d < D; ++d) acc[d] += src[4 + d];
        }

        // ---- exact np tie semantics ----
        const float dmin = sqrtf(m2);     // precise
        int bestk = ka;
        if (sqrtf(m2b) == dmin) {
            // rare (~1e-5 rows): distinct d2 values collide after sqrt ->
            // np picks the first index over the dist array. Re-scan exactly.
            const float* cr  = codes + (size_t)l * K * D;
            const float* wp  = w2g + l * K;
            for (int k = 0; k < K; ++k) {
                float cross = 0.f;
                #pragma unroll
                for (int d = 0; d < D; ++d) cross = fmaf(h[d], cr[k * D + d], cross);
                float d2 = (h2 - 2.f * cross) + wp[k];
                d2 = fmaxf(d2, 1e-12f);
                if (sqrtf(d2) == dmin) { bestk = k; break; }
            }
        }

        const float invs = 1.f / s;
        float* osoft = out + (size_t)p * CH + l * D;
        #pragma unroll
        for (int qq = 0; qq < 4; ++qq) {
            float4 v;
            v.x = acc[qq * 4 + 0] * invs;
            v.y = acc[qq * 4 + 1] * invs;
            v.z = acc[qq * 4 + 2] * invs;
            v.w = acc[qq * 4 + 3] * invs;
            reinterpret_cast<float4*>(osoft)[qq] = v;
        }

        const float4* bc = reinterpret_cast<const float4*>(codes + ((size_t)l * K + bestk) * D);
        float* ohard = out + (size_t)BHW * CH + (size_t)p * CH + l * D;
        #pragma unroll
        for (int qq = 0; qq < 4; ++qq)
            reinterpret_cast<float4*>(ohard)[qq] = bc[qq];

        out[(size_t)2 * BHW * CH + (size_t)p * L + l] = (float)bestk;
    }
}
} // namespace

extern "C" void kernel_launch(void* const* d_in, const int* in_sizes, int n_in,
                              void* d_out, int out_size, void* d_ws, size_t ws_size,
                              hipStream_t stream) {
    const float* z     = (const float*)d_in[0];
    const float* codes = (const float*)d_in[1];
    float* out         = (float*)d_out;
    float* w2          = (float*)d_ws;   // 8*512 floats = 16 KB

    compute_w2<<<dim3(L * K / 256), 256, 0, stream>>>(codes, w2);
    dim3 grid(BHW / PPB, L);
    soft_hard_encode<<<grid, TPB, 0, stream>>>(z, codes, w2, out);
}

// Round 9
// 85.004 us; speedup vs baseline: 1.4743x; 1.0033x over previous
//
#include <hip/hip_runtime.h>

namespace {
constexpr int BHW = 16384;   // 16*32*32 pixels
constexpr int L   = 8;
constexpr int K   = 512;
constexpr int D   = 16;
constexpr int HW  = 1024;    // 32*32
constexpr int CH  = 128;     // L*D
constexpr int TPB = 512;     // 8 waves = 2 pixel-groups x 4 K-quarters
constexpr int PPB = 128;     // pixels per block
constexpr int KQ  = K / 4;   // 128 codes per wave

// ---- tiny precompute: ||code||^2, sequential fmaf chain (rounding contract) ----
__global__ void compute_w2(const float* __restrict__ codes, float* __restrict__ w2) {
    int i = blockIdx.x * 256 + threadIdx.x;          // 0..4095
    const float* c = codes + (size_t)i * D;
    float s = 0.f;
    #pragma unroll
    for (int d = 0; d < D; ++d) s = fmaf(c[d], c[d], s);
    w2[i] = s;
}

__global__ __launch_bounds__(TPB, 6) void soft_hard_encode(
    const float* __restrict__ z,      // [16,128,32,32]
    const float* __restrict__ codes,  // [8,512,16]
    const float* __restrict__ w2g,    // [8,512]
    float* __restrict__ out)          // soft | hard | idx(float)
{
    // union: [0, 8192) floats = codes tile [512][16]; [8192, 8704) = w2 [512]
    // after the k-loop (barrier) the same space is reused as merge buffer
    __shared__ float smem[K * D + K];          // 34816 B
    float* lds_c  = smem;                      // [512][16]
    float* lds_w2 = smem + K * D;              // [512]

    const int tid  = threadIdx.x;
    const int lane = tid & 63;
    const int wv   = __builtin_amdgcn_readfirstlane(tid) >> 6;  // 0..7, uniform
    const int q    = wv & 3;         // uniform: K-quarter
    const int pgrp = wv >> 2;        // uniform: pixel group
    const int l    = blockIdx.y;
    const int prow = pgrp * 64 + lane;               // 0..127 within block
    const int p    = blockIdx.x * PPB + prow;        // global pixel

    // ---- stage codes[l] + w2 into LDS (one row per thread, coalesced) ----
    {
        const float4* src = reinterpret_cast<const float4*>(codes + ((size_t)l * K + tid) * D);
        float4* dst = reinterpret_cast<float4*>(lds_c + (size_t)tid * D);
        dst[0] = src[0]; dst[1] = src[1]; dst[2] = src[2]; dst[3] = src[3];
        lds_w2[tid] = w2g[l * K + tid];
    }

    // ---- load h (overlaps staging; coalesced across lanes) ----
    const int b  = p >> 10;
    const int yx = p & (HW - 1);
    const float* zp = z + ((size_t)(b * CH + l * D)) * HW + yx;
    float h[D];
    #pragma unroll
    for (int d = 0; d < D; ++d) h[d] = zp[(size_t)d * HW];
    float h2 = 0.f;
    #pragma unroll
    for (int d = 0; d < D; ++d) h2 = fmaf(h[d], h[d], h2);

    __syncthreads();

    // ---- this wave's K range (uniform LDS address -> broadcast reads) ----
    const int kbeg = q * KQ;
    const float* crow = lds_c + (size_t)kbeg * D;
    const float* w2p  = lds_w2 + kbeg;

    // min (with first-occurrence index) and second-min VALUE of clamped d2
    float m2 = 1e30f, m2b = 1e30f;
    int   ka = 0;
    float s = 0.f;
    float acc[D];
    #pragma unroll
    for (int d = 0; d < D; ++d) acc[d] = 0.f;

    #pragma unroll 1
    for (int k = 0; k < KQ; ++k) {
        const float4* cp = reinterpret_cast<const float4*>(crow + (size_t)k * D);
        const float4 c0 = cp[0], c1 = cp[1], c2 = cp[2], c3 = cp[3];
        const float c[D] = {c0.x, c0.y, c0.z, c0.w, c1.x, c1.y, c1.z, c1.w,
                            c2.x, c2.y, c2.z, c2.w, c3.x, c3.y, c3.z, c3.w};
        const float w2k = w2p[k];

        // ---- rounding contract: single sequential fmaf chain (UNCHANGED) ----
        float cross = 0.f;
        #pragma unroll
        for (int d = 0; d < D; ++d) cross = fmaf(h[d], c[d], cross);
        float d2 = (h2 - 2.f * cross) + w2k;
        d2 = fmaxf(d2, 1e-12f);

        // ---- lean exact min tracking on d2 ----
        const float t = fmaxf(d2, m2);     // old m2
        m2b = fminf(m2b, t);               // second-min value (no index)
        const bool lt = d2 < m2;
        m2 = lt ? d2 : m2;
        ka = lt ? k  : ka;

        // ---- soft path: fast sqrt + exp2 (loose tolerance) ----
        const float dist = __builtin_amdgcn_sqrtf(d2);
        const float w = __builtin_amdgcn_exp2f(dist * -1.44269504088896340736f);
        s += w;
        #pragma unroll
        for (int d = 0; d < D; ++d) acc[d] = fmaf(w, c[d], acc[d]);
    }

    // ---- all waves done reading lds_c: safe to reuse LDS as merge buffer ----
    __syncthreads();
    float* part = smem;                  // [3][PPB][20]
    if (q != 0) {
        float* dst = part + ((size_t)(q - 1) * PPB + prow) * 20;
        dst[0] = s;
        dst[1] = m2;
        dst[2] = m2b;
        dst[3] = __int_as_float(ka + kbeg);
        #pragma unroll
        for (int d = 0; d < D; ++d) dst[4 + d] = acc[d];
    }
    __syncthreads();
    if (q == 0) {
        #pragma unroll
        for (int j = 0; j < 3; ++j) {
            const float* src = part + ((size_t)j * PPB + prow) * 20;
            s += src[0];
            const float mj  = src[1];
            const float mbj = src[2];
            const int   kj  = __float_as_int(src[3]);
            // global 2nd-min = min( max(minA,minB), min(min2A,min2B) )
            m2b = fminf(fminf(m2b, mbj), fmaxf(m2, mj));
            const bool lt = mj < m2;     // strict: tie keeps lower-quarter index
            m2 = lt ? mj : m2;
            ka = lt ? kj : ka;
            #pragma unroll
            for (int d = 0; d < D; ++d) acc[d] += src[4 + d];
        }

        // ---- exact np tie semantics ----
        const float dmin = sqrtf(m2);     // precise
        int bestk = ka;
        if (sqrtf(m2b) == dmin) {
            // rare (~1e-5 rows): distinct d2 values collide after sqrt ->
            // np picks the first index over the dist array. Re-scan exactly.
            const float* cr  = codes + (size_t)l * K * D;
            const float* wp  = w2g + l * K;
            for (int k = 0; k < K; ++k) {
                float cross = 0.f;
                #pragma unroll
                for (int d = 0; d < D; ++d) cross = fmaf(h[d], cr[k * D + d], cross);
                float d2 = (h2 - 2.f * cross) + wp[k];
                d2 = fmaxf(d2, 1e-12f);
                if (sqrtf(d2) == dmin) { bestk = k; break; }
            }
        }

        const float invs = 1.f / s;
        float* osoft = out + (size_t)p * CH + l * D;
        #pragma unroll
        for (int qq = 0; qq < 4; ++qq) {
            float4 v;
            v.x = acc[qq * 4 + 0] * invs;
            v.y = acc[qq * 4 + 1] * invs;
            v.z = acc[qq * 4 + 2] * invs;
            v.w = acc[qq * 4 + 3] * invs;
            reinterpret_cast<float4*>(osoft)[qq] = v;
        }

        const float4* bc = reinterpret_cast<const float4*>(codes + ((size_t)l * K + bestk) * D);
        float* ohard = out + (size_t)BHW * CH + (size_t)p * CH + l * D;
        #pragma unroll
        for (int qq = 0; qq < 4; ++qq)
            reinterpret_cast<float4*>(ohard)[qq] = bc[qq];

        out[(size_t)2 * BHW * CH + (size_t)p * L + l] = (float)bestk;
    }
}
} // namespace

extern "C" void kernel_launch(void* const* d_in, const int* in_sizes, int n_in,
                              void* d_out, int out_size, void* d_ws, size_t ws_size,
                              hipStream_t stream) {
    const float* z     = (const float*)d_in[0];
    const float* codes = (const float*)d_in[1];
    float* out         = (float*)d_out;
    float* w2          = (float*)d_ws;   // 8*512 floats = 16 KB

    compute_w2<<<dim3(L * K / 256), 256, 0, stream>>>(codes, w2);
    dim3 grid(BHW / PPB, L);
    soft_hard_encode<<<grid, TPB, 0, stream>>>(z, codes, w2, out);
}

// Round 10
// 72.171 us; speedup vs baseline: 1.7365x; 1.1778x over previous
//
#include <hip/hip_runtime.h>
#include <hip/hip_bf16.h>

typedef float  f32x4  __attribute__((ext_vector_type(4)));
typedef short  s16x8  __attribute__((ext_vector_type(8)));
typedef __bf16 bf16x8 __attribute__((ext_vector_type(8)));
typedef unsigned int u32x2 __attribute__((ext_vector_type(2)));
typedef unsigned int u32x4 __attribute__((ext_vector_type(4)));

namespace {
constexpr int BHW = 16384, L = 8, K = 512, D = 16, HW = 1024, CH = 128;
constexpr int TPB = 512;   // 8 waves; wave = 16 pixels x all 512 codes
constexpr int PPB = 128;   // pixels per block
// ws: cA [L][K][32] bf16 (hi|lo interleaved) + w2g [L][K] f32
constexpr size_t WS_CA_ELEMS = (size_t)L * K * 32;                       // 131072
constexpr size_t WS_NEED = WS_CA_ELEMS * 2 + (size_t)L * K * 4;         // 278528 (== R5's, known to fit)

__device__ __forceinline__ f32x4 mfma16(s16x8 a, s16x8 b, f32x4 c) {
  return __builtin_amdgcn_mfma_f32_16x16x32_bf16(
      __builtin_bit_cast(bf16x8, a), __builtin_bit_cast(bf16x8, b), c, 0, 0, 0);
}
__device__ __forceinline__ unsigned short bfh(float x) {
  return __builtin_bit_cast(unsigned short, __float2bfloat16(x));
}
__device__ __forceinline__ float bf2f(unsigned short u) {
  return __bfloat162float(__builtin_bit_cast(__hip_bfloat16, u));
}

// ---- precompute: split codes into bf16 hi/lo (A-frag layout) + exact-chain ||c||^2 ----
__global__ void repack(const float* __restrict__ codes,
                       unsigned short* __restrict__ cA, float* __restrict__ w2g) {
  int i = blockIdx.x * 256 + threadIdx.x;          // (l,k) 0..4095
  const float* c = codes + (size_t)i * D;
  float s = 0.f;
  #pragma unroll
  for (int d = 0; d < D; ++d) s = fmaf(c[d], c[d], s);   // rounding-contract chain
  w2g[i] = s;
  unsigned short* dst = cA + (size_t)i * 32;
  #pragma unroll
  for (int d = 0; d < D; ++d) {
    unsigned short hi = bfh(c[d]);
    unsigned short lo = bfh(c[d] - bf2f(hi));
    dst[d] = hi; dst[16 + d] = lo;                 // kappa-layout [hi(16) | lo(16)]
  }
}

__global__ __launch_bounds__(TPB, 4) void enc_mfma(
    const float* __restrict__ z,            // [16,128,32,32]
    const float* __restrict__ codes,        // [8,512,16] f32 (hard path + rescan)
    const unsigned short* __restrict__ cA,  // [8,512,32] bf16 split
    const float* __restrict__ w2g,          // [8,512]
    float* __restrict__ out)                // soft | hard | idx(float)
{
  __shared__ unsigned short cH[512 * 18];   // c_hi[k][d], rows padded to 18 (CF u16 gathers)
  __shared__ unsigned short cL[512 * 18];
  __shared__ float w2s[512];
  __shared__ unsigned short Pl[8][16][32];  // per-wave P_hi staging (XOR-swizzled 8B units)
  __shared__ unsigned short hH[128][16];
  __shared__ unsigned short hL[128][16];
  __shared__ float h2s[128];
  __shared__ float ssum[8][16];
  __shared__ int   bks[8][16];

  const int tid  = threadIdx.x;
  const int l    = blockIdx.y;
  const int bx   = blockIdx.x;
  const int bimg = bx >> 3;
  const int yx0  = (bx & 7) * 128;

  // ---- stage h f32 into cH region (transient), coalesced over yx ----
  float* hstg = (float*)cH;                 // [128][17] (pad for bank spread)
  {
    const int i = tid & 127, dc = tid >> 7;
    #pragma unroll
    for (int it = 0; it < 4; ++it) {
      int d = dc + it * 4;
      hstg[i * 17 + d] = z[((size_t)(bimg * CH + l * D + d)) * HW + yx0 + i];
    }
  }
  __syncthreads();
  if (tid < 128) {
    float h[16]; float h2 = 0.f;
    #pragma unroll
    for (int d = 0; d < 16; ++d) h[d] = hstg[tid * 17 + d];
    #pragma unroll
    for (int d = 0; d < 16; ++d) h2 = fmaf(h[d], h[d], h2);   // exact chain (rescan uses it)
    h2s[tid] = h2;
    #pragma unroll
    for (int d = 0; d < 16; ++d) {
      unsigned short hi = bfh(h[d]);
      hH[tid][d] = hi;
      hL[tid][d] = bfh(h[d] - bf2f(hi));
    }
  }
  __syncthreads();
  // ---- stage codes (overwrites hstg region) ----
  {
    const unsigned short* src = cA + ((size_t)l * K + tid) * 32;
    #pragma unroll
    for (int d = 0; d < 16; ++d) { cH[tid * 18 + d] = src[d]; cL[tid * 18 + d] = src[16 + d]; }
    w2s[tid] = w2g[l * K + tid];
  }
  __syncthreads();

  // ---- wave setup ----
  const int wv   = __builtin_amdgcn_readfirstlane(tid >> 6);  // 0..7
  const int lane = tid & 63;
  const int cl   = lane & 15;
  const int g    = lane >> 4;
  const int pw   = wv * 16;                 // wave's local pixel base
  const int myp  = pw + cl;

  // QK B-frags (h): B1=[h_hi|h_hi], B2=[h_lo|h_lo]; lane col=pixel=cl, kappa-run g*8
  s16x8 B1 = *(const s16x8*)&hH[myp][(g & 1) * 8];
  s16x8 B2 = *(const s16x8*)&hL[myp][(g & 1) * 8];
  const float h2 = h2s[myp];

  // QK A base: code row = ck*32 + t*16 + cl, kappa-run g*8  (s16x8 units: 4/code row)
  const s16x8* Ab = (const s16x8*)(cA + (size_t)l * K * 32) + (cl * 4 + g);

  // P_lds swizzled unit offsets (bytes), per-lane consts
  char* Pb = (char*)&Pl[wv][0][0] + cl * 64;
  const int w0off = ((g    ) ^ (cl & 7)) << 3;   // t=0 unit = g
  const int w1off = ((4 + g) ^ (cl & 7)) << 3;   // t=1 unit = 4+g
  const int r0off = ((2 * g    ) ^ (cl & 7)) << 3;
  const int r1off = ((2 * g + 1) ^ (cl & 7)) << 3;

  float m2k = 1e30f, m2bk = 1e30f, s = 0.f;
  f32x4 pv = {0.f, 0.f, 0.f, 0.f};

  #pragma unroll 4
  for (int ck = 0; ck < 16; ++ck) {
    // --- QK: exact-split cross via 4 MFMAs (2 per 16-code tile) ---
    s16x8 A0 = Ab[ck * 128];
    s16x8 A1 = Ab[ck * 128 + 64];
    f32x4 T0 = {0.f, 0.f, 0.f, 0.f}, T1 = {0.f, 0.f, 0.f, 0.f};
    T0 = mfma16(A0, B1, T0); T0 = mfma16(A0, B2, T0);
    T1 = mfma16(A1, B1, T1); T1 = mfma16(A1, B2, T1);

    f32x4 W0 = *(const f32x4*)&w2s[ck * 32 + g * 4];
    f32x4 W1 = *(const f32x4*)&w2s[ck * 32 + 16 + g * 4];

    float wt[8];
    #pragma unroll
    for (int t = 0; t < 2; ++t) {
      #pragma unroll
      for (int r = 0; r < 4; ++r) {
        float T  = t ? T1[r] : T0[r];
        float Wk = t ? W1[r] : W0[r];
        float d2 = fmaf(-2.f, T, h2) + Wk;
        d2 = fmaxf(d2, 1e-12f);
        int kloc = ck * 32 + t * 16 + g * 4 + r;
        // key = d2 with low 9 mantissa bits replaced by k: one-float (min,argmin)
        float key = __int_as_float((__float_as_int(d2) & 0xFFFFFE00) | kloc);
        m2bk = __builtin_amdgcn_fmed3f(key, m2k, m2bk);  // second-min tracking
        m2k  = fminf(m2k, key);
        float dist = __builtin_amdgcn_sqrtf(d2);
        float w = __builtin_amdgcn_exp2f(dist * -1.44269504088896340736f);
        s += w;
        wt[t * 4 + r] = w;
      }
    }
    // --- P_hi pack -> per-wave LDS (swizzled), then PV A-frag read ---
    #pragma unroll
    for (int t = 0; t < 2; ++t) {
      unsigned p01 = (unsigned)bfh(wt[t*4+0]) | ((unsigned)bfh(wt[t*4+1]) << 16);
      unsigned p23 = (unsigned)bfh(wt[t*4+2]) | ((unsigned)bfh(wt[t*4+3]) << 16);
      *(unsigned*)(Pb + (t ? w1off : w0off) + 0) = p01;
      *(unsigned*)(Pb + (t ? w1off : w0off) + 4) = p23;
    }
    u32x2 pa0 = *(const u32x2*)(Pb + r0off);
    u32x2 pa1 = *(const u32x2*)(Pb + r1off);
    u32x4 pau; pau[0] = pa0[0]; pau[1] = pa0[1]; pau[2] = pa1[0]; pau[3] = pa1[1];
    s16x8 PA = __builtin_bit_cast(s16x8, pau);
    // --- PV B-frags: c_hi/c_lo[k][d], lane col=d=cl, codes 8g..8g+7 (CF via pad-18) ---
    s16x8 Bh, Bl;
    #pragma unroll
    for (int j = 0; j < 8; ++j) {
      Bh[j] = (short)cH[(ck * 32 + 8 * g + j) * 18 + cl];
      Bl[j] = (short)cL[(ck * 32 + 8 * g + j) * 18 + cl];
    }
    pv = mfma16(PA, Bh, pv);
    pv = mfma16(PA, Bl, pv);
  }

  // ---- reduce over the 4 lanes sharing each pixel (xor 16, 32) ----
  #pragma unroll
  for (int off = 16; off < 64; off <<= 1) {
    s += __shfl_xor(s, off);
    float m2o  = __shfl_xor(m2k, off);
    float m2bo = __shfl_xor(m2bk, off);
    m2bk = fminf(fminf(m2bk, m2bo), fmaxf(m2k, m2o));
    m2k  = fminf(m2k, m2o);
  }
  int ka = __float_as_int(m2k) & 511;
  float d2min = __int_as_float(__float_as_int(m2k)  & 0xFFFFFE00);
  float d2sec = __int_as_float(__float_as_int(m2bk) & 0xFFFFFE00);
  bool trig = (d2sec - d2min) < 0.02f;   // covers split-eps + key clobber + sqrt-ties

  if (lane < 16) { ssum[wv][lane] = s; bks[wv][lane] = ka; }

  // ---- rare exact rescan (np-exact chain + precise sqrt, first occurrence) ----
  unsigned long long mask = __ballot(lane < 16 && trig);
  while (mask) {
    int pl = __ffsll((long long)mask) - 1; mask &= mask - 1;
    float hh[16];
    #pragma unroll
    for (int d = 0; d < 16; ++d)
      hh[d] = z[((size_t)(bimg * CH + l * D + d)) * HW + yx0 + pw + pl];
    float h2x = h2s[pw + pl];
    float bm = 1e30f; int bkk = 0;
    for (int rnd = 0; rnd < 8; ++rnd) {
      int k = rnd * 64 + lane;
      const float* cr = codes + ((size_t)l * K + k) * D;
      float cross = 0.f;
      #pragma unroll
      for (int d = 0; d < 16; ++d) cross = fmaf(hh[d], cr[d], cross);
      float d2 = (h2x - 2.f * cross) + w2g[l * K + k];
      d2 = fmaxf(d2, 1e-12f);
      float dist = sqrtf(d2);                 // precise, matches np
      if (dist < bm) { bm = dist; bkk = k; }  // k ascending per lane
    }
    #pragma unroll
    for (int off = 1; off < 64; off <<= 1) {
      float bo = __shfl_xor(bm, off); int ko = __shfl_xor(bkk, off);
      if (bo < bm || (bo == bm && ko < bkk)) { bm = bo; bkk = ko; }
    }
    if (lane == 0) bks[wv][pl] = bkk;
  }

  // ---- epilogue ----
  const int pg0 = bimg * HW + yx0;
  // soft: PV D-frag ownership (d = cl, pixels pw + g*4 + r)
  f32x4 sv = *(const f32x4*)&ssum[wv][g * 4];
  #pragma unroll
  for (int r = 0; r < 4; ++r) {
    float inv = __builtin_amdgcn_rcpf(sv[r]);
    out[(size_t)(pg0 + pw + g * 4 + r) * CH + l * D + cl] = pv[r] * inv;
  }
  // hard: lane (pixel = cl, d-run = g*4), exact f32 codes
  int kk = bks[wv][cl];
  float4 cv = *(const float4*)&codes[((size_t)l * K + kk) * D + g * 4];
  *(float4*)&out[(size_t)BHW * CH + (size_t)(pg0 + pw + cl) * CH + l * D + g * 4] = cv;
  if (lane < 16)
    out[(size_t)2 * BHW * CH + (size_t)(pg0 + pw + cl) * L + l] = (float)kk;
}
} // namespace

extern "C" void kernel_launch(void* const* d_in, const int* in_sizes, int n_in,
                              void* d_out, int out_size, void* d_ws, size_t ws_size,
                              hipStream_t stream) {
  const float* z     = (const float*)d_in[0];
  const float* codes = (const float*)d_in[1];
  float* out         = (float*)d_out;
  unsigned short* cA = (unsigned short*)d_ws;                  // 256 KB
  float* w2g         = (float*)((char*)d_ws + WS_CA_ELEMS * 2); // +16 KB (ws >= 278528 verified in R5)

  repack<<<dim3(L * K / 256), 256, 0, stream>>>(codes, cA, w2g);
  dim3 grid(BHW / PPB, L);
  enc_mfma<<<grid, TPB, 0, stream>>>(z, codes, cA, w2g, out);
}